// Round 5
// baseline (1816.065 us; speedup 1.0000x reference)
//
#include <hip/hip_runtime.h>

// RelativeAxialAttention on MI355X (gfx950). Round 5: latency/efficiency pass.
// K=48, G=8, DK=8, DV=16, CIN=64, B = 2304. Inputs runtime-detected f32/bf16.
//
// Pipeline: detect -> zero -> emb -> gram(+xT f32 transpose) -> fold(weffT) ->
//   stage1 (coalesced xT GEMM -> qkv bf16 + sim stats) -> simcoef ->
//   attn2 (1 head/block: logits+softmax+sv/sve -> pre2 + out stats) ->
//   outcoef -> final (BN+pairsum+transpose).
// Workspace: EXACTLY round-4's 113481264 B footprint (known to fit):
//   xT f32 (28.3 MB) aliases pre2 (56.6 MB) region; qkv bf16 56.6 MB.

typedef unsigned short u16;

#define N_S 110592
#define N_B 2304

__device__ __forceinline__ float b2f(u16 v) {
    return __builtin_bit_cast(float, ((unsigned)v) << 16);
}
__device__ __forceinline__ u16 f2b(float f) {
    unsigned u = __builtin_bit_cast(unsigned, f);
    u = (u + 0x7FFFu + ((u >> 16) & 1u)) >> 16;
    return (u16)u;
}
__device__ __forceinline__ float ldf(const void* p, int idx, int f32) {
    return f32 ? ((const float*)p)[idx] : b2f(((const u16*)p)[idx]);
}

// ---------------- dtype detection ----------------
__global__ void k_detect(const u16* X, int* flag) {
    __shared__ int tot;
    if (threadIdx.x == 0) tot = 0;
    __syncthreads();
    int cnt = 0;
#pragma unroll
    for (int k = 0; k < 8; k++) {
        u16 v = X[(threadIdx.x * 8 + k) * 2];
        int e = (v >> 7) & 0xFF;
        cnt += (e >= 0x70 && e <= 0x8F) ? 1 : 0;
    }
    atomicAdd(&tot, cnt);
    __syncthreads();
    if (threadIdx.x == 0) flag[0] = (tot < 1024) ? 1 : 0;   // 1 = f32
}

// ---------------- zero stats region ----------------
__global__ void k_zero(float* w) {
    for (int i = blockIdx.x * blockDim.x + threadIdx.x; i < 4720; i += gridDim.x * blockDim.x)
        w[i] = 0.0f;
}

// ---------------- emb tables (bf16; keT pre-transposed) ----------------
__global__ void k_emb(const void* rel, const int* fidx, const int* flag,
                      u16* qe, u16* keT, u16* ve) {
    int f32 = flag[0];
    int t = blockIdx.x * 256 + threadIdx.x;
    if (t >= 2304) return;
    int i = t / 48, j = t % 48;
    int fij = fidx[i * 48 + j];
    int fji = fidx[j * 48 + i];
#pragma unroll
    for (int c = 0; c < 8; c++) {
        qe[c * 2304 + t]  = f2b(ldf(rel, c * 95 + fij, f32));
        keT[c * 2304 + t] = f2b(ldf(rel, (8 + c) * 95 + fji, f32));
    }
#pragma unroll
    for (int c = 0; c < 16; c++)
        ve[c * 2304 + t] = f2b(ldf(rel, (16 + c) * 95 + fij, f32));
}

// ---------------- x gram + xT (f32, [s][c]) emit ----------------
__global__ __launch_bounds__(256) void k_gram(const void* Xv, const int* flag,
                                              float* musum, float* gram, float* xT) {
    __shared__ float xs[64 * 64];   // [s][c]
    int f32 = flag[0];
    int tid = threadIdx.x;
    int cb1 = tid >> 4, cb2 = tid & 15;    // 4x4 tile: rows cb1*4.., cols cb2*4..
    float acc[4][4];
#pragma unroll
    for (int a = 0; a < 4; a++)
#pragma unroll
        for (int b = 0; b < 4; b++) acc[a][b] = 0.0f;
    float mur = 0.0f;
    for (int tile = blockIdx.x; tile < 1728; tile += gridDim.x) {
        int s0 = tile * 64;
        __syncthreads();
#pragma unroll
        for (int r = 0; r < 4; r++) {
            int idx4 = tid + 256 * r;
            int c = idx4 >> 4, sl = (idx4 & 15) * 4;
            float v0, v1, v2, v3;
            if (f32) {
                float4 u = *(const float4*)((const float*)Xv + (size_t)c * N_S + s0 + sl);
                v0 = u.x; v1 = u.y; v2 = u.z; v3 = u.w;
            } else {
                ushort4 u = *(const ushort4*)((const u16*)Xv + (size_t)c * N_S + s0 + sl);
                v0 = b2f(u.x); v1 = b2f(u.y); v2 = b2f(u.z); v3 = b2f(u.w);
            }
            xs[(sl + 0) * 64 + c] = v0;
            xs[(sl + 1) * 64 + c] = v1;
            xs[(sl + 2) * 64 + c] = v2;
            xs[(sl + 3) * 64 + c] = v3;
        }
        __syncthreads();
        for (int s = 0; s < 64; s++) {
            float4 av = *(const float4*)(xs + s * 64 + cb1 * 4);
            float4 bv = *(const float4*)(xs + s * 64 + cb2 * 4);
            float aa[4] = {av.x, av.y, av.z, av.w};
            float bb[4] = {bv.x, bv.y, bv.z, bv.w};
#pragma unroll
            for (int a = 0; a < 4; a++)
#pragma unroll
                for (int b = 0; b < 4; b++) acc[a][b] += aa[a] * bb[b];
        }
        if (tid < 64) {
            for (int s = 0; s < 64; s++) mur += xs[s * 64 + tid];
        }
        {   // xT write: thread -> (s = tid>>2, cq = (tid&3)*16)
            int s = tid >> 2, cq = (tid & 3) * 16;
            float4* dst = (float4*)(xT + (size_t)(s0 + s) * 64 + cq);
            const float4* src = (const float4*)(xs + s * 64 + cq);
            dst[0] = src[0]; dst[1] = src[1]; dst[2] = src[2]; dst[3] = src[3];
        }
    }
#pragma unroll
    for (int a = 0; a < 4; a++)
#pragma unroll
        for (int b = 0; b < 4; b++)
            atomicAdd(&gram[(cb1 * 4 + a) * 64 + (cb2 * 4 + b)], acc[a][b]);
    if (tid < 64) atomicAdd(&musum[tid], mur);
}

// ---------------- fold BN into weights -> weffT[c][o], beff[o] ----------------
__global__ __launch_bounds__(256) void k_fold(const void* Wkv, const void* Wq,
        const void* gkv, const void* bkv, const void* gq, const void* bq,
        const int* flag, const float* musum, const float* gram,
        float* weffT, float* beff) {
    int f32 = flag[0];
    int o = threadIdx.x;
    float gam, bet;
    float w[64];
    if (o < 192) {
#pragma unroll
        for (int c = 0; c < 64; c++) w[c] = ldf(Wkv, o * 64 + c, f32);
        gam = ldf(gkv, o, f32); bet = ldf(bkv, o, f32);
    } else {
        int oq = o - 192;
#pragma unroll
        for (int c = 0; c < 64; c++) w[c] = ldf(Wq, oq * 64 + c, f32);
        gam = ldf(gq, oq, f32); bet = ldf(bq, oq, f32);
    }
    const float inv = 1.0f / (float)N_S;
    float mean = 0.0f;
#pragma unroll
    for (int c = 0; c < 64; c++) mean += w[c] * musum[c];
    mean *= inv;
    float e2 = 0.0f;
    for (int c = 0; c < 64; c++) {
        float t = 0.0f;
#pragma unroll
        for (int c2 = 0; c2 < 64; c2++) t += w[c2] * gram[c * 64 + c2];
        e2 += w[c] * t;
    }
    e2 *= inv;
    float var = e2 - mean * mean;
    if (var < 0.0f) var = 0.0f;
    float sc = gam * rsqrtf(var + 1e-5f);
#pragma unroll
    for (int c = 0; c < 64; c++) weffT[c * 256 + o] = sc * w[c];
    beff[o] = bet - sc * mean;
}

// ---------------- stage1: qkv GEMM (coalesced xT) + sim stats ----------------
// qkv layout: ((b*8+g)*32 + rr)*48, rr: 0-7 q, 8-15 k, 16-31 v.
__global__ __launch_bounds__(256, 4) void k_stage1(const float* xT, const float* weffT,
        const float* beff, const u16* qe, const u16* keT,
        const void* fqrp, const void* fkrp, const int* flag, float* sstat, u16* qkv) {
    __shared__ float xs[64 * 48];        // [c][h]
    __shared__ float qT[8 * 48 * 8];     // [g][i][c]
    __shared__ float kk[8 * 8 * 48];     // [g][c][j]
    __shared__ float red[48];
    int b = blockIdx.x, tid = threadIdx.x;
    // coalesced load of xT[b]: 768 float4
#pragma unroll
    for (int r = 0; r < 3; r++) {
        int hh = (tid & 15) + 16 * r;       // 0..47
        int cq = (tid >> 4) * 4;            // 0..60
        float4 xv = *(const float4*)(xT + ((size_t)hh * N_B + b) * 64 + cq);
        xs[(cq + 0) * 48 + hh] = xv.x;
        xs[(cq + 1) * 48 + hh] = xv.y;
        xs[(cq + 2) * 48 + hh] = xv.z;
        xs[(cq + 3) * 48 + hh] = xv.w;
    }
    if (tid < 48) red[tid] = 0.0f;
    __syncthreads();
    {   // GEMM: thread -> 4 rows (a4*4..+3) x 12 h (hq..hq+11)
        int a4 = tid >> 2;
        int hq = (tid & 3) * 12;
        float acc[4][12];
        {
            float4 bs = *(const float4*)(beff + a4 * 4);
            float bb[4] = {bs.x, bs.y, bs.z, bs.w};
#pragma unroll
            for (int r4 = 0; r4 < 4; r4++)
#pragma unroll
                for (int j = 0; j < 12; j++) acc[r4][j] = bb[r4];
        }
#pragma unroll 4
        for (int c = 0; c < 64; c++) {
            float4 w4 = *(const float4*)(weffT + c * 256 + a4 * 4);
            const float* xrow = xs + c * 48 + hq;
            float4 x0 = *(const float4*)(xrow);
            float4 x1 = *(const float4*)(xrow + 4);
            float4 x2 = *(const float4*)(xrow + 8);
            float xr[12] = {x0.x, x0.y, x0.z, x0.w, x1.x, x1.y, x1.z, x1.w,
                            x2.x, x2.y, x2.z, x2.w};
            float wv[4] = {w4.x, w4.y, w4.z, w4.w};
#pragma unroll
            for (int r4 = 0; r4 < 4; r4++)
#pragma unroll
                for (int j = 0; j < 12; j++) acc[r4][j] += wv[r4] * xr[j];
        }
#pragma unroll
        for (int r4 = 0; r4 < 4; r4++) {
            int o = a4 * 4 + r4;
            int g, rr;
            if (o < 192) { g = o / 24; rr = 8 + (o - g * 24); }
            else { g = (o - 192) >> 3; rr = (o - 192) & 7; }
            u16* gd = qkv + ((b * 256 + g * 32 + rr) * 48 + hq);
            *(ushort4*)(gd + 0) = make_ushort4(f2b(acc[r4][0]), f2b(acc[r4][1]), f2b(acc[r4][2]), f2b(acc[r4][3]));
            *(ushort4*)(gd + 4) = make_ushort4(f2b(acc[r4][4]), f2b(acc[r4][5]), f2b(acc[r4][6]), f2b(acc[r4][7]));
            *(ushort4*)(gd + 8) = make_ushort4(f2b(acc[r4][8]), f2b(acc[r4][9]), f2b(acc[r4][10]), f2b(acc[r4][11]));
            if (rr < 8) {
#pragma unroll
                for (int j = 0; j < 12; j++) qT[(g * 48 + hq + j) * 8 + rr] = acc[r4][j];
            } else if (rr < 16) {
                float* kd = kk + (g * 8 + rr - 8) * 48 + hq;
                *(float4*)(kd + 0) = make_float4(acc[r4][0], acc[r4][1], acc[r4][2], acc[r4][3]);
                *(float4*)(kd + 4) = make_float4(acc[r4][4], acc[r4][5], acc[r4][6], acc[r4][7]);
                *(float4*)(kd + 8) = make_float4(acc[r4][8], acc[r4][9], acc[r4][10], acc[r4][11]);
            }
        }
    }
    __syncthreads();
    float fqr = ldf(fqrp, 0, flag[0]), fkr = ldf(fkrp, 0, flag[0]);
    float sum[24], sq[24];
#pragma unroll
    for (int k = 0; k < 24; k++) { sum[k] = 0.0f; sq[k] = 0.0f; }
    for (int r = 0; r < 3; r++) {
        int chunk = tid + 256 * r;
        if (chunk >= 576) break;
        int i = chunk / 12, j0 = (chunk % 12) * 4;
        float qv[8][4], kv[8][4];
#pragma unroll
        for (int c = 0; c < 8; c++) {
            ushort4 uq = *(const ushort4*)(qe + c * 2304 + i * 48 + j0);
            ushort4 uk = *(const ushort4*)(keT + c * 2304 + i * 48 + j0);
            qv[c][0] = b2f(uq.x); qv[c][1] = b2f(uq.y); qv[c][2] = b2f(uq.z); qv[c][3] = b2f(uq.w);
            kv[c][0] = b2f(uk.x); kv[c][1] = b2f(uk.y); kv[c][2] = b2f(uk.z); kv[c][3] = b2f(uk.w);
        }
#pragma unroll
        for (int g = 0; g < 8; g++) {
            float4 qa = *(const float4*)(qT + (g * 48 + i) * 8);
            float4 qb = *(const float4*)(qT + (g * 48 + i) * 8 + 4);
            float qreg[8] = {qa.x, qa.y, qa.z, qa.w, qb.x, qb.y, qb.z, qb.w};
            float zq[4] = {0, 0, 0, 0}, zr[4] = {0, 0, 0, 0}, zk[4] = {0, 0, 0, 0};
#pragma unroll
            for (int c = 0; c < 8; c++) {
                float qi = qreg[c];
                float4 kf4 = *(const float4*)(kk + (g * 8 + c) * 48 + j0);
                zq[0] += qi * kf4.x; zq[1] += qi * kf4.y; zq[2] += qi * kf4.z; zq[3] += qi * kf4.w;
                zr[0] += qi * qv[c][0]; zr[1] += qi * qv[c][1]; zr[2] += qi * qv[c][2]; zr[3] += qi * qv[c][3];
                zk[0] += kf4.x * kv[c][0]; zk[1] += kf4.y * kv[c][1]; zk[2] += kf4.z * kv[c][2]; zk[3] += kf4.w * kv[c][3];
            }
#pragma unroll
            for (int u = 0; u < 4; u++) {
                float a = zq[u];        sum[g] += a;       sq[g] += a * a;
                float r1 = zr[u] * fqr; sum[8 + g] += r1;  sq[8 + g] += r1 * r1;
                float r2 = zk[u] * fkr; sum[16 + g] += r2; sq[16 + g] += r2 * r2;
            }
        }
    }
#pragma unroll
    for (int k = 0; k < 24; k++) {
        float s = sum[k], q = sq[k];
        for (int off = 32; off >= 1; off >>= 1) { s += __shfl_xor(s, off); q += __shfl_xor(q, off); }
        if ((tid & 63) == 0) { atomicAdd(&red[k], s); atomicAdd(&red[24 + k], q); }
    }
    __syncthreads();
    if (tid < 48) atomicAdd(&sstat[tid], red[tid]);
}

__global__ void k_simcoef(const float* sstat, const void* gsim, const int* flag, float* scoef) {
    int ch = threadIdx.x;
    if (ch >= 24) return;
    const float n = 2304.0f * 2304.0f;
    float mean = sstat[ch] / n;
    float var = sstat[24 + ch] / n - mean * mean;
    if (var < 0.0f) var = 0.0f;
    scoef[ch] = ldf(gsim, ch, flag[0]) * rsqrtf(var + 1e-5f);
}

// ---------------- attn2: one block per (b, g) ----------------
__global__ __launch_bounds__(256, 8) void k_attn2(const u16* qkv,
        const u16* qe, const u16* keT, const u16* ve,
        const float* scoef, const void* fqrp, const void* fkrp,
        const void* fsvp, const void* fsvep, const int* flag,
        float* ostat, u16* pre2) {
    __shared__ float qT[48 * 12];   // [i][c] (pad 8->12)
    __shared__ float kf[8 * 48];    // [c][j]
    __shared__ float vf[16 * 48];   // [c][j]
    __shared__ float z[48 * 52];
    int b = blockIdx.x, g = blockIdx.y, tid = threadIdx.x;
    const u16* src = qkv + ((size_t)b * 256 + g * 32) * 48;
#pragma unroll
    for (int r = 0; r < 2; r++) {
        int idx = tid + 256 * r;
        if (idx < 384) {
            int row = idx / 12, hq = (idx % 12) * 4;
            ushort4 u = *(const ushort4*)(src + row * 48 + hq);
            if (row < 8) {
                qT[(hq + 0) * 12 + row] = b2f(u.x);
                qT[(hq + 1) * 12 + row] = b2f(u.y);
                qT[(hq + 2) * 12 + row] = b2f(u.z);
                qT[(hq + 3) * 12 + row] = b2f(u.w);
            } else if (row < 16) {
                *(float4*)(kf + (row - 8) * 48 + hq) =
                    make_float4(b2f(u.x), b2f(u.y), b2f(u.z), b2f(u.w));
            } else {
                *(float4*)(vf + (row - 16) * 48 + hq) =
                    make_float4(b2f(u.x), b2f(u.y), b2f(u.z), b2f(u.w));
            }
        }
    }
    __syncthreads();
    int f32 = flag[0];
    float fqr = ldf(fqrp, 0, f32), fkr = ldf(fkrp, 0, f32);
    float fsv = ldf(fsvp, 0, f32), fsve = ldf(fsvep, 0, f32);
    float c0 = scoef[g], c1 = scoef[8 + g] * fqr, c2 = scoef[16 + g] * fkr;
    // logits
    for (int r = 0; r < 3; r++) {
        int chunk = tid + 256 * r;
        if (chunk >= 576) break;
        int i = chunk / 12, j0 = (chunk % 12) * 4;
        float4 qa = *(const float4*)(qT + i * 12);
        float4 qb = *(const float4*)(qT + i * 12 + 4);
        float qreg[8] = {qa.x, qa.y, qa.z, qa.w, qb.x, qb.y, qb.z, qb.w};
        float zq[4] = {0, 0, 0, 0}, zr[4] = {0, 0, 0, 0}, zk[4] = {0, 0, 0, 0};
#pragma unroll
        for (int c = 0; c < 8; c++) {
            float qi = qreg[c];
            float4 kf4 = *(const float4*)(kf + c * 48 + j0);
            ushort4 uq = *(const ushort4*)(qe + c * 2304 + i * 48 + j0);
            ushort4 uk = *(const ushort4*)(keT + c * 2304 + i * 48 + j0);
            zq[0] += qi * kf4.x; zq[1] += qi * kf4.y; zq[2] += qi * kf4.z; zq[3] += qi * kf4.w;
            zr[0] += qi * b2f(uq.x); zr[1] += qi * b2f(uq.y); zr[2] += qi * b2f(uq.z); zr[3] += qi * b2f(uq.w);
            zk[0] += kf4.x * b2f(uk.x); zk[1] += kf4.y * b2f(uk.y); zk[2] += kf4.z * b2f(uk.z); zk[3] += kf4.w * b2f(uk.w);
        }
        float4 o4;
        o4.x = c0 * zq[0] + c1 * zr[0] + c2 * zk[0];
        o4.y = c0 * zq[1] + c1 * zr[1] + c2 * zk[1];
        o4.z = c0 * zq[2] + c1 * zr[2] + c2 * zk[2];
        o4.w = c0 * zq[3] + c1 * zr[3] + c2 * zk[3];
        *(float4*)(z + i * 52 + j0) = o4;
    }
    __syncthreads();
    {   // softmax: 4 waves x 12 rows
        int wv = tid >> 6, lane = tid & 63;
        for (int rr = 0; rr < 12; rr++) {
            int i = wv * 12 + rr;
            float val = (lane < 48) ? z[i * 52 + lane] : -1e30f;
            float m = val;
            for (int off = 32; off >= 1; off >>= 1) m = fmaxf(m, __shfl_xor(m, off));
            float e = (lane < 48) ? __expf(val - m) : 0.0f;
            float s = e;
            for (int off = 32; off >= 1; off >>= 1) s += __shfl_xor(s, off);
            if (lane < 48) z[i * 52 + lane] = e / s;
        }
    }
    __syncthreads();
    {   // sv / sve
        int c = tid >> 4, u = tid & 15;
        float sumA = 0, sqA = 0, sumB = 0, sqB = 0;
#pragma unroll
        for (int r = 0; r < 3; r++) {
            int i = u + 16 * r;
            float sv = 0.0f, se = 0.0f;
#pragma unroll
            for (int j4 = 0; j4 < 12; j4++) {
                float4 sm = *(const float4*)(z + i * 52 + j4 * 4);
                float4 vv = *(const float4*)(vf + c * 48 + j4 * 4);
                ushort4 eu = *(const ushort4*)(ve + c * 2304 + i * 48 + j4 * 4);
                sv += sm.x * vv.x + sm.y * vv.y + sm.z * vv.z + sm.w * vv.w;
                se += sm.x * b2f(eu.x) + sm.y * b2f(eu.y) + sm.z * b2f(eu.z) + sm.w * b2f(eu.w);
            }
            float a = sv * fsv, bb = se * fsve;
            *(ushort2*)(pre2 + ((size_t)(b * 128 + g * 16 + c) * 48 + i) * 2) =
                make_ushort2(f2b(a), f2b(bb));
            sumA += a; sqA += a * a; sumB += bb; sqB += bb * bb;
        }
#pragma unroll
        for (int off = 1; off <= 8; off <<= 1) {
            sumA += __shfl_xor(sumA, off); sqA += __shfl_xor(sqA, off);
            sumB += __shfl_xor(sumB, off); sqB += __shfl_xor(sqB, off);
        }
        if (u == 0) {
            int ch2 = g * 32 + c * 2;
            atomicAdd(&ostat[ch2 * 2 + 0], sumA);
            atomicAdd(&ostat[ch2 * 2 + 1], sqA);
            atomicAdd(&ostat[ch2 * 2 + 2], sumB);
            atomicAdd(&ostat[ch2 * 2 + 3], sqB);
        }
    }
}

__global__ void k_outcoef(const float* ostat, const void* gout, const void* bout,
                          const int* flag, float* ocoef) {
    int f32 = flag[0];
    int o = threadIdx.x;   // 256
    const float n = 110592.0f;
    float mean = ostat[o * 2] / n;
    float var = ostat[o * 2 + 1] / n - mean * mean;
    if (var < 0.0f) var = 0.0f;
    float sc = ldf(gout, o, f32) * rsqrtf(var + 1e-5f);
    ocoef[o * 2] = sc;
    ocoef[o * 2 + 1] = ldf(bout, o, f32) - mean * sc;
}

// ---------------- final: BN + pair-sum + transpose ----------------
__global__ __launch_bounds__(256) void k_final(const u16* pre2, const float* ocoef,
                                               const int* flag, void* outp) {
    __shared__ float tile[48 * 49];
    int f32 = flag[0];
    int ch = blockIdx.x, w = blockIdx.y, tid = threadIdx.x;
    float sc0 = ocoef[(ch * 2) * 2],     sh0 = ocoef[(ch * 2) * 2 + 1];
    float sc1 = ocoef[(ch * 2 + 1) * 2], sh1 = ocoef[(ch * 2 + 1) * 2 + 1];
    float shs = sh0 + sh1;
#pragma unroll
    for (int r = 0; r < 9; r++) {
        int idx = tid + 256 * r;
        int d = idx / 48, i = idx % 48;
        ushort2 p = ((const ushort2*)pre2)[(size_t)((w * 48 + d) * 128 + ch) * 48 + i];
        tile[d * 49 + i] = b2f(p.x) * sc0 + b2f(p.y) * sc1 + shs;
    }
    __syncthreads();
#pragma unroll
    for (int r = 0; r < 9; r++) {
        int idx = tid + 256 * r;
        int i = idx / 48, d = idx % 48;
        float v = tile[d * 49 + i];
        int oidx = ch * N_S + i * 2304 + w * 48 + d;
        if (f32) ((float*)outp)[oidx] = v;
        else     ((u16*)outp)[oidx] = f2b(v);
    }
}

extern "C" void kernel_launch(void* const* d_in, const int* in_sizes, int n_in,
                              void* d_out, int out_size, void* d_ws, size_t ws_size,
                              hipStream_t stream) {
    const void* X    = d_in[0];
    const void* Wkv  = d_in[1];
    const void* Wq   = d_in[2];
    const void* gkv  = d_in[3];
    const void* bkv  = d_in[4];
    const void* gq   = d_in[5];
    const void* bq   = d_in[6];
    const void* gsim = d_in[7];
    // d_in[8] (b_sim) unused: additive per-channel constant, softmax-invariant.
    const void* gout = d_in[9];
    const void* bout = d_in[10];
    const void* rel  = d_in[11];
    const void* fqrp = d_in[12];
    const void* fkrp = d_in[13];
    const void* fsvp = d_in[14];
    const void* fsvep= d_in[15];
    const int* fidx  = (const int*)d_in[16];

    float* W      = (float*)d_ws;
    float* musum  = W;            // 64
    float* gram   = W + 64;       // 4096
    float* sstat  = W + 4160;     // 48
    float* ostat  = W + 4208;     // 512  (zero region ends 4720)
    float* weffT  = W + 4720;     // 16384 ([c][o])
    float* beff   = W + 21104;    // 256
    float* scoef  = W + 21360;    // 24
    float* ocoef  = W + 21384;    // 512
    int*   flag   = (int*)(W + 21896);    // 1 (+3 pad)
    u16*   qe     = (u16*)(W + 21900);    // 8*2304 u16
    u16*   keT    = (u16*)(W + 31116);    // 8*2304 u16
    u16*   ve     = (u16*)(W + 40332);    // 16*2304 u16; ends at 58764
    // region1 (14155776 f): xT f32 (7077888 f) then clobbered by pre2 (28311552 u16)
    float* xT     = W + 58764;
    u16*   pre2   = (u16*)(W + 58764);
    u16*   qkv    = (u16*)(W + 58764 + 14155776);   // 28311552 u16

    k_detect<<<1, 256, 0, stream>>>((const u16*)X, flag);
    k_zero<<<8, 256, 0, stream>>>(W);
    k_emb<<<9, 256, 0, stream>>>(rel, fidx, flag, qe, keT, ve);
    k_gram<<<256, 256, 0, stream>>>(X, flag, musum, gram, xT);
    k_fold<<<1, 256, 0, stream>>>(Wkv, Wq, gkv, bkv, gq, bq, flag, musum, gram, weffT, beff);
    k_stage1<<<2304, 256, 0, stream>>>(xT, weffT, beff, qe, keT, fqrp, fkrp, flag, sstat, qkv);
    k_simcoef<<<1, 32, 0, stream>>>(sstat, gsim, flag, scoef);
    k_attn2<<<dim3(2304, 8), 256, 0, stream>>>(qkv, qe, keT, ve, scoef,
                                               fqrp, fkrp, fsvp, fsvep, flag, ostat, pre2);
    k_outcoef<<<1, 256, 0, stream>>>(ostat, gout, bout, flag, ocoef);
    k_final<<<dim3(128, 48), 256, 0, stream>>>(pre2, ocoef, flag, d_out);
}

// Round 6
// 1299.280 us; speedup vs baseline: 1.3977x; 1.3977x over previous
//
#include <hip/hip_runtime.h>

// RelativeAxialAttention on MI355X (gfx950). Round 6: de-spill + true coalescing.
// K=48, G=8, DK=8, DV=16, CIN=64, B = 2304. Inputs runtime-detected f32/bf16.
//
// Round-5 lesson (counters): __launch_bounds__ min-waves forced VGPR 32/128 caps
// -> register arrays spilled to scratch -> 2.2 GB/dispatch HBM traffic. NEVER
// cap below the kernel's natural live-set (~56 attn2, ~150 stage1).
//
// Pipeline: detect -> zero -> emb -> gram(+x2[b][h][c] emit) -> fold(weffT) ->
//   stage1 (contiguous x2 GEMM -> qkv bf16 + sim stats) -> simcoef ->
//   attn2 (1 head/block) -> outcoef -> final.
// Workspace: same 113.5 MB footprint as rounds 4/5 (known to fit):
//   x2 f32 (28.3 MB) aliases pre2 (56.6 MB); qkv bf16 56.6 MB.

typedef unsigned short u16;

#define N_S 110592
#define N_B 2304

__device__ __forceinline__ float b2f(u16 v) {
    return __builtin_bit_cast(float, ((unsigned)v) << 16);
}
__device__ __forceinline__ u16 f2b(float f) {
    unsigned u = __builtin_bit_cast(unsigned, f);
    u = (u + 0x7FFFu + ((u >> 16) & 1u)) >> 16;
    return (u16)u;
}
__device__ __forceinline__ float ldf(const void* p, int idx, int f32) {
    return f32 ? ((const float*)p)[idx] : b2f(((const u16*)p)[idx]);
}

// ---------------- dtype detection ----------------
__global__ void k_detect(const u16* X, int* flag) {
    __shared__ int tot;
    if (threadIdx.x == 0) tot = 0;
    __syncthreads();
    int cnt = 0;
#pragma unroll
    for (int k = 0; k < 8; k++) {
        u16 v = X[(threadIdx.x * 8 + k) * 2];
        int e = (v >> 7) & 0xFF;
        cnt += (e >= 0x70 && e <= 0x8F) ? 1 : 0;
    }
    atomicAdd(&tot, cnt);
    __syncthreads();
    if (threadIdx.x == 0) flag[0] = (tot < 1024) ? 1 : 0;   // 1 = f32
}

// ---------------- zero stats region ----------------
__global__ void k_zero(float* w) {
    for (int i = blockIdx.x * blockDim.x + threadIdx.x; i < 4720; i += gridDim.x * blockDim.x)
        w[i] = 0.0f;
}

// ---------------- emb tables (bf16; keT pre-transposed) ----------------
__global__ void k_emb(const void* rel, const int* fidx, const int* flag,
                      u16* qe, u16* keT, u16* ve) {
    int f32 = flag[0];
    int t = blockIdx.x * 256 + threadIdx.x;
    if (t >= 2304) return;
    int i = t / 48, j = t % 48;
    int fij = fidx[i * 48 + j];
    int fji = fidx[j * 48 + i];
#pragma unroll
    for (int c = 0; c < 8; c++) {
        qe[c * 2304 + t]  = f2b(ldf(rel, c * 95 + fij, f32));
        keT[c * 2304 + t] = f2b(ldf(rel, (8 + c) * 95 + fji, f32));
    }
#pragma unroll
    for (int c = 0; c < 16; c++)
        ve[c * 2304 + t] = f2b(ldf(rel, (16 + c) * 95 + fij, f32));
}

// ---------------- x gram + x2[b][h][c] emit ----------------
__global__ __launch_bounds__(256) void k_gram(const void* Xv, const int* flag,
                                              float* musum, float* gram, float* x2) {
    __shared__ float xs[64 * 64];   // [s][c]
    int f32 = flag[0];
    int tid = threadIdx.x;
    int cb1 = tid >> 4, cb2 = tid & 15;
    float acc[4][4];
#pragma unroll
    for (int a = 0; a < 4; a++)
#pragma unroll
        for (int b = 0; b < 4; b++) acc[a][b] = 0.0f;
    float mur = 0.0f;
    for (int tile = blockIdx.x; tile < 1728; tile += gridDim.x) {
        int s0 = tile * 64;
        __syncthreads();
#pragma unroll
        for (int r = 0; r < 4; r++) {
            int idx4 = tid + 256 * r;
            int c = idx4 >> 4, sl = (idx4 & 15) * 4;
            float v0, v1, v2, v3;
            if (f32) {
                float4 u = *(const float4*)((const float*)Xv + (size_t)c * N_S + s0 + sl);
                v0 = u.x; v1 = u.y; v2 = u.z; v3 = u.w;
            } else {
                ushort4 u = *(const ushort4*)((const u16*)Xv + (size_t)c * N_S + s0 + sl);
                v0 = b2f(u.x); v1 = b2f(u.y); v2 = b2f(u.z); v3 = b2f(u.w);
            }
            xs[(sl + 0) * 64 + c] = v0;
            xs[(sl + 1) * 64 + c] = v1;
            xs[(sl + 2) * 64 + c] = v2;
            xs[(sl + 3) * 64 + c] = v3;
        }
        __syncthreads();
        for (int s = 0; s < 64; s++) {
            float4 av = *(const float4*)(xs + s * 64 + cb1 * 4);
            float4 bv = *(const float4*)(xs + s * 64 + cb2 * 4);
            float aa[4] = {av.x, av.y, av.z, av.w};
            float bb[4] = {bv.x, bv.y, bv.z, bv.w};
#pragma unroll
            for (int a = 0; a < 4; a++)
#pragma unroll
                for (int b = 0; b < 4; b++) acc[a][b] += aa[a] * bb[b];
        }
        if (tid < 64) {
            for (int s = 0; s < 64; s++) mur += xs[s * 64 + tid];
        }
        {   // x2[b][h][c] write: 64B contiguous per thread (full lines, no amplification)
            int sl = tid >> 2, cq = (tid & 3) * 16;
            int s = s0 + sl;
            int b = s % N_B, h = s / N_B;   // tile never straddles h (2304 % 64 == 0)
            float4* dst = (float4*)(x2 + ((size_t)b * 48 + h) * 64 + cq);
            const float4* src = (const float4*)(xs + sl * 64 + cq);
            dst[0] = src[0]; dst[1] = src[1]; dst[2] = src[2]; dst[3] = src[3];
        }
    }
#pragma unroll
    for (int a = 0; a < 4; a++)
#pragma unroll
        for (int b = 0; b < 4; b++)
            atomicAdd(&gram[(cb1 * 4 + a) * 64 + (cb2 * 4 + b)], acc[a][b]);
    if (tid < 64) atomicAdd(&musum[tid], mur);
}

// ---------------- fold BN into weights -> weffT[c][o], beff[o] ----------------
__global__ __launch_bounds__(256) void k_fold(const void* Wkv, const void* Wq,
        const void* gkv, const void* bkv, const void* gq, const void* bq,
        const int* flag, const float* musum, const float* gram,
        float* weffT, float* beff) {
    int f32 = flag[0];
    int o = threadIdx.x;
    float gam, bet;
    float w[64];
    if (o < 192) {
#pragma unroll
        for (int c = 0; c < 64; c++) w[c] = ldf(Wkv, o * 64 + c, f32);
        gam = ldf(gkv, o, f32); bet = ldf(bkv, o, f32);
    } else {
        int oq = o - 192;
#pragma unroll
        for (int c = 0; c < 64; c++) w[c] = ldf(Wq, oq * 64 + c, f32);
        gam = ldf(gq, oq, f32); bet = ldf(bq, oq, f32);
    }
    const float inv = 1.0f / (float)N_S;
    float mean = 0.0f;
#pragma unroll
    for (int c = 0; c < 64; c++) mean += w[c] * musum[c];
    mean *= inv;
    float e2 = 0.0f;
    for (int c = 0; c < 64; c++) {
        float t = 0.0f;
#pragma unroll
        for (int c2 = 0; c2 < 64; c2++) t += w[c2] * gram[c * 64 + c2];
        e2 += w[c] * t;
    }
    e2 *= inv;
    float var = e2 - mean * mean;
    if (var < 0.0f) var = 0.0f;
    float sc = gam * rsqrtf(var + 1e-5f);
#pragma unroll
    for (int c = 0; c < 64; c++) weffT[c * 256 + o] = sc * w[c];
    beff[o] = bet - sc * mean;
}

// ---------------- stage1: qkv GEMM (contiguous x2) + sim stats ----------------
// qkv layout: ((b*8+g)*32 + rr)*48, rr: 0-7 q, 8-15 k, 16-31 v.
// NOTE: plain launch_bounds — stats loop needs ~150 VGPRs; capping spills (round 5).
__global__ __launch_bounds__(256) void k_stage1(const float* x2, const float* weffT,
        const float* beff, const u16* qe, const u16* keT,
        const void* fqrp, const void* fkrp, const int* flag, float* sstat, u16* qkv) {
    __shared__ float xs[64 * 52];        // [c][h] pad 52 (16B-aligned rows)
    __shared__ float qT[8 * 48 * 8];     // [g][i][c]
    __shared__ float kk[8 * 8 * 48];     // [g][c][j]
    __shared__ float red[48];
    int b = blockIdx.x, tid = threadIdx.x;
    // contiguous load of x2[b] (12 KB), transpose [h][c] -> xs[c][h]
#pragma unroll
    for (int r = 0; r < 3; r++) {
        int idx = tid + 256 * r;            // 768 float4
        int h = idx >> 4, cq4 = idx & 15;
        float4 xv = *(const float4*)(x2 + (size_t)b * 3072 + idx * 4);
        xs[(cq4 * 4 + 0) * 52 + h] = xv.x;
        xs[(cq4 * 4 + 1) * 52 + h] = xv.y;
        xs[(cq4 * 4 + 2) * 52 + h] = xv.z;
        xs[(cq4 * 4 + 3) * 52 + h] = xv.w;
    }
    if (tid < 48) red[tid] = 0.0f;
    __syncthreads();
    {   // GEMM: thread -> 4 rows (a4*4..+3) x 12 h (hq..hq+11)
        int a4 = tid >> 2;
        int hq = (tid & 3) * 12;
        float acc[4][12];
        {
            float4 bs = *(const float4*)(beff + a4 * 4);
            float bb[4] = {bs.x, bs.y, bs.z, bs.w};
#pragma unroll
            for (int r4 = 0; r4 < 4; r4++)
#pragma unroll
                for (int j = 0; j < 12; j++) acc[r4][j] = bb[r4];
        }
#pragma unroll 4
        for (int c = 0; c < 64; c++) {
            float4 w4 = *(const float4*)(weffT + c * 256 + a4 * 4);
            const float* xrow = xs + c * 52 + hq;
            float4 x0 = *(const float4*)(xrow);
            float4 x1 = *(const float4*)(xrow + 4);
            float4 x2r = *(const float4*)(xrow + 8);
            float xr[12] = {x0.x, x0.y, x0.z, x0.w, x1.x, x1.y, x1.z, x1.w,
                            x2r.x, x2r.y, x2r.z, x2r.w};
            float wv[4] = {w4.x, w4.y, w4.z, w4.w};
#pragma unroll
            for (int r4 = 0; r4 < 4; r4++)
#pragma unroll
                for (int j = 0; j < 12; j++) acc[r4][j] += wv[r4] * xr[j];
        }
#pragma unroll
        for (int r4 = 0; r4 < 4; r4++) {
            int o = a4 * 4 + r4;
            int g, rr;
            if (o < 192) { g = o / 24; rr = 8 + (o - g * 24); }
            else { g = (o - 192) >> 3; rr = (o - 192) & 7; }
            u16* gd = qkv + ((b * 256 + g * 32 + rr) * 48 + hq);
            *(ushort4*)(gd + 0) = make_ushort4(f2b(acc[r4][0]), f2b(acc[r4][1]), f2b(acc[r4][2]), f2b(acc[r4][3]));
            *(ushort4*)(gd + 4) = make_ushort4(f2b(acc[r4][4]), f2b(acc[r4][5]), f2b(acc[r4][6]), f2b(acc[r4][7]));
            *(ushort4*)(gd + 8) = make_ushort4(f2b(acc[r4][8]), f2b(acc[r4][9]), f2b(acc[r4][10]), f2b(acc[r4][11]));
            if (rr < 8) {
#pragma unroll
                for (int j = 0; j < 12; j++) qT[(g * 48 + hq + j) * 8 + rr] = acc[r4][j];
            } else if (rr < 16) {
                float* kd = kk + (g * 8 + rr - 8) * 48 + hq;
                *(float4*)(kd + 0) = make_float4(acc[r4][0], acc[r4][1], acc[r4][2], acc[r4][3]);
                *(float4*)(kd + 4) = make_float4(acc[r4][4], acc[r4][5], acc[r4][6], acc[r4][7]);
                *(float4*)(kd + 8) = make_float4(acc[r4][8], acc[r4][9], acc[r4][10], acc[r4][11]);
            }
        }
    }
    __syncthreads();
    float fqr = ldf(fqrp, 0, flag[0]), fkr = ldf(fkrp, 0, flag[0]);
    float sum[24], sq[24];
#pragma unroll
    for (int k = 0; k < 24; k++) { sum[k] = 0.0f; sq[k] = 0.0f; }
    for (int r = 0; r < 3; r++) {
        int chunk = tid + 256 * r;
        if (chunk >= 576) break;
        int i = chunk / 12, j0 = (chunk % 12) * 4;
        float qv[8][4], kv[8][4];
#pragma unroll
        for (int c = 0; c < 8; c++) {
            ushort4 uq = *(const ushort4*)(qe + c * 2304 + i * 48 + j0);
            ushort4 uk = *(const ushort4*)(keT + c * 2304 + i * 48 + j0);
            qv[c][0] = b2f(uq.x); qv[c][1] = b2f(uq.y); qv[c][2] = b2f(uq.z); qv[c][3] = b2f(uq.w);
            kv[c][0] = b2f(uk.x); kv[c][1] = b2f(uk.y); kv[c][2] = b2f(uk.z); kv[c][3] = b2f(uk.w);
        }
#pragma unroll
        for (int g = 0; g < 8; g++) {
            float4 qa = *(const float4*)(qT + (g * 48 + i) * 8);
            float4 qb = *(const float4*)(qT + (g * 48 + i) * 8 + 4);
            float qreg[8] = {qa.x, qa.y, qa.z, qa.w, qb.x, qb.y, qb.z, qb.w};
            float zq[4] = {0, 0, 0, 0}, zr[4] = {0, 0, 0, 0}, zk[4] = {0, 0, 0, 0};
#pragma unroll
            for (int c = 0; c < 8; c++) {
                float qi = qreg[c];
                float4 kf4 = *(const float4*)(kk + (g * 8 + c) * 48 + j0);
                zq[0] += qi * kf4.x; zq[1] += qi * kf4.y; zq[2] += qi * kf4.z; zq[3] += qi * kf4.w;
                zr[0] += qi * qv[c][0]; zr[1] += qi * qv[c][1]; zr[2] += qi * qv[c][2]; zr[3] += qi * qv[c][3];
                zk[0] += kf4.x * kv[c][0]; zk[1] += kf4.y * kv[c][1]; zk[2] += kf4.z * kv[c][2]; zk[3] += kf4.w * kv[c][3];
            }
#pragma unroll
            for (int u = 0; u < 4; u++) {
                float a = zq[u];        sum[g] += a;       sq[g] += a * a;
                float r1 = zr[u] * fqr; sum[8 + g] += r1;  sq[8 + g] += r1 * r1;
                float r2 = zk[u] * fkr; sum[16 + g] += r2; sq[16 + g] += r2 * r2;
            }
        }
    }
#pragma unroll
    for (int k = 0; k < 24; k++) {
        float s = sum[k], q = sq[k];
        for (int off = 32; off >= 1; off >>= 1) { s += __shfl_xor(s, off); q += __shfl_xor(q, off); }
        if ((tid & 63) == 0) { atomicAdd(&red[k], s); atomicAdd(&red[24 + k], q); }
    }
    __syncthreads();
    if (tid < 48) atomicAdd(&sstat[tid], red[tid]);
}

__global__ void k_simcoef(const float* sstat, const void* gsim, const int* flag, float* scoef) {
    int ch = threadIdx.x;
    if (ch >= 24) return;
    const float n = 2304.0f * 2304.0f;
    float mean = sstat[ch] / n;
    float var = sstat[24 + ch] / n - mean * mean;
    if (var < 0.0f) var = 0.0f;
    scoef[ch] = ldf(gsim, ch, flag[0]) * rsqrtf(var + 1e-5f);
}

// ---------------- attn2: one block per (b, g) ----------------
// NOTE: plain launch_bounds — (256,8) in round 5 forced VGPR 32 -> scratch spill
// -> 2.2 GB/dispatch HBM traffic (the 932 us regression).
__global__ __launch_bounds__(256) void k_attn2(const u16* qkv,
        const u16* qe, const u16* keT, const u16* ve,
        const float* scoef, const void* fqrp, const void* fkrp,
        const void* fsvp, const void* fsvep, const int* flag,
        float* ostat, u16* pre2) {
    __shared__ float qT[48 * 12];   // [i][c] (pad 8->12)
    __shared__ float kf[8 * 48];    // [c][j]
    __shared__ float vf[16 * 48];   // [c][j]
    __shared__ float z[48 * 52];
    int b = blockIdx.x, g = blockIdx.y, tid = threadIdx.x;
    const u16* src = qkv + ((size_t)b * 256 + g * 32) * 48;
#pragma unroll
    for (int r = 0; r < 2; r++) {
        int idx = tid + 256 * r;
        if (idx < 384) {
            int row = idx / 12, hq = (idx % 12) * 4;
            ushort4 u = *(const ushort4*)(src + row * 48 + hq);
            if (row < 8) {
                qT[(hq + 0) * 12 + row] = b2f(u.x);
                qT[(hq + 1) * 12 + row] = b2f(u.y);
                qT[(hq + 2) * 12 + row] = b2f(u.z);
                qT[(hq + 3) * 12 + row] = b2f(u.w);
            } else if (row < 16) {
                *(float4*)(kf + (row - 8) * 48 + hq) =
                    make_float4(b2f(u.x), b2f(u.y), b2f(u.z), b2f(u.w));
            } else {
                *(float4*)(vf + (row - 16) * 48 + hq) =
                    make_float4(b2f(u.x), b2f(u.y), b2f(u.z), b2f(u.w));
            }
        }
    }
    __syncthreads();
    int f32 = flag[0];
    float fqr = ldf(fqrp, 0, f32), fkr = ldf(fkrp, 0, f32);
    float fsv = ldf(fsvp, 0, f32), fsve = ldf(fsvep, 0, f32);
    float c0 = scoef[g], c1 = scoef[8 + g] * fqr, c2 = scoef[16 + g] * fkr;
    // logits
    for (int r = 0; r < 3; r++) {
        int chunk = tid + 256 * r;
        if (chunk >= 576) break;
        int i = chunk / 12, j0 = (chunk % 12) * 4;
        float4 qa = *(const float4*)(qT + i * 12);
        float4 qb = *(const float4*)(qT + i * 12 + 4);
        float qreg[8] = {qa.x, qa.y, qa.z, qa.w, qb.x, qb.y, qb.z, qb.w};
        float zq[4] = {0, 0, 0, 0}, zr[4] = {0, 0, 0, 0}, zk[4] = {0, 0, 0, 0};
#pragma unroll
        for (int c = 0; c < 8; c++) {
            float qi = qreg[c];
            float4 kf4 = *(const float4*)(kf + c * 48 + j0);
            ushort4 uq = *(const ushort4*)(qe + c * 2304 + i * 48 + j0);
            ushort4 uk = *(const ushort4*)(keT + c * 2304 + i * 48 + j0);
            zq[0] += qi * kf4.x; zq[1] += qi * kf4.y; zq[2] += qi * kf4.z; zq[3] += qi * kf4.w;
            zr[0] += qi * b2f(uq.x); zr[1] += qi * b2f(uq.y); zr[2] += qi * b2f(uq.z); zr[3] += qi * b2f(uq.w);
            zk[0] += kf4.x * b2f(uk.x); zk[1] += kf4.y * b2f(uk.y); zk[2] += kf4.z * b2f(uk.z); zk[3] += kf4.w * b2f(uk.w);
        }
        float4 o4;
        o4.x = c0 * zq[0] + c1 * zr[0] + c2 * zk[0];
        o4.y = c0 * zq[1] + c1 * zr[1] + c2 * zk[1];
        o4.z = c0 * zq[2] + c1 * zr[2] + c2 * zk[2];
        o4.w = c0 * zq[3] + c1 * zr[3] + c2 * zk[3];
        *(float4*)(z + i * 52 + j0) = o4;
    }
    __syncthreads();
    {   // softmax: 4 waves x 12 rows
        int wv = tid >> 6, lane = tid & 63;
        for (int rr = 0; rr < 12; rr++) {
            int i = wv * 12 + rr;
            float val = (lane < 48) ? z[i * 52 + lane] : -1e30f;
            float m = val;
            for (int off = 32; off >= 1; off >>= 1) m = fmaxf(m, __shfl_xor(m, off));
            float e = (lane < 48) ? __expf(val - m) : 0.0f;
            float s = e;
            for (int off = 32; off >= 1; off >>= 1) s += __shfl_xor(s, off);
            if (lane < 48) z[i * 52 + lane] = e / s;
        }
    }
    __syncthreads();
    {   // sv / sve
        int c = tid >> 4, u = tid & 15;
        float sumA = 0, sqA = 0, sumB = 0, sqB = 0;
#pragma unroll
        for (int r = 0; r < 3; r++) {
            int i = u + 16 * r;
            float sv = 0.0f, se = 0.0f;
#pragma unroll
            for (int j4 = 0; j4 < 12; j4++) {
                float4 sm = *(const float4*)(z + i * 52 + j4 * 4);
                float4 vv = *(const float4*)(vf + c * 48 + j4 * 4);
                ushort4 eu = *(const ushort4*)(ve + c * 2304 + i * 48 + j4 * 4);
                sv += sm.x * vv.x + sm.y * vv.y + sm.z * vv.z + sm.w * vv.w;
                se += sm.x * b2f(eu.x) + sm.y * b2f(eu.y) + sm.z * b2f(eu.z) + sm.w * b2f(eu.w);
            }
            float a = sv * fsv, bb = se * fsve;
            *(ushort2*)(pre2 + ((size_t)(b * 128 + g * 16 + c) * 48 + i) * 2) =
                make_ushort2(f2b(a), f2b(bb));
            sumA += a; sqA += a * a; sumB += bb; sqB += bb * bb;
        }
#pragma unroll
        for (int off = 1; off <= 8; off <<= 1) {
            sumA += __shfl_xor(sumA, off); sqA += __shfl_xor(sqA, off);
            sumB += __shfl_xor(sumB, off); sqB += __shfl_xor(sqB, off);
        }
        if (u == 0) {
            int ch2 = g * 32 + c * 2;
            atomicAdd(&ostat[ch2 * 2 + 0], sumA);
            atomicAdd(&ostat[ch2 * 2 + 1], sqA);
            atomicAdd(&ostat[ch2 * 2 + 2], sumB);
            atomicAdd(&ostat[ch2 * 2 + 3], sqB);
        }
    }
}

__global__ void k_outcoef(const float* ostat, const void* gout, const void* bout,
                          const int* flag, float* ocoef) {
    int f32 = flag[0];
    int o = threadIdx.x;   // 256
    const float n = 110592.0f;
    float mean = ostat[o * 2] / n;
    float var = ostat[o * 2 + 1] / n - mean * mean;
    if (var < 0.0f) var = 0.0f;
    float sc = ldf(gout, o, f32) * rsqrtf(var + 1e-5f);
    ocoef[o * 2] = sc;
    ocoef[o * 2 + 1] = ldf(bout, o, f32) - mean * sc;
}

// ---------------- final: BN + pair-sum + transpose ----------------
__global__ __launch_bounds__(256) void k_final(const u16* pre2, const float* ocoef,
                                               const int* flag, void* outp) {
    __shared__ float tile[48 * 49];
    int f32 = flag[0];
    int ch = blockIdx.x, w = blockIdx.y, tid = threadIdx.x;
    float sc0 = ocoef[(ch * 2) * 2],     sh0 = ocoef[(ch * 2) * 2 + 1];
    float sc1 = ocoef[(ch * 2 + 1) * 2], sh1 = ocoef[(ch * 2 + 1) * 2 + 1];
    float shs = sh0 + sh1;
#pragma unroll
    for (int r = 0; r < 9; r++) {
        int idx = tid + 256 * r;
        int d = idx / 48, i = idx % 48;
        ushort2 p = ((const ushort2*)pre2)[(size_t)((w * 48 + d) * 128 + ch) * 48 + i];
        tile[d * 49 + i] = b2f(p.x) * sc0 + b2f(p.y) * sc1 + shs;
    }
    __syncthreads();
#pragma unroll
    for (int r = 0; r < 9; r++) {
        int idx = tid + 256 * r;
        int i = idx / 48, d = idx % 48;
        float v = tile[d * 49 + i];
        int oidx = ch * N_S + i * 2304 + w * 48 + d;
        if (f32) ((float*)outp)[oidx] = v;
        else     ((u16*)outp)[oidx] = f2b(v);
    }
}

extern "C" void kernel_launch(void* const* d_in, const int* in_sizes, int n_in,
                              void* d_out, int out_size, void* d_ws, size_t ws_size,
                              hipStream_t stream) {
    const void* X    = d_in[0];
    const void* Wkv  = d_in[1];
    const void* Wq   = d_in[2];
    const void* gkv  = d_in[3];
    const void* bkv  = d_in[4];
    const void* gq   = d_in[5];
    const void* bq   = d_in[6];
    const void* gsim = d_in[7];
    // d_in[8] (b_sim) unused: additive per-channel constant, softmax-invariant.
    const void* gout = d_in[9];
    const void* bout = d_in[10];
    const void* rel  = d_in[11];
    const void* fqrp = d_in[12];
    const void* fkrp = d_in[13];
    const void* fsvp = d_in[14];
    const void* fsvep= d_in[15];
    const int* fidx  = (const int*)d_in[16];

    float* W      = (float*)d_ws;
    float* musum  = W;            // 64
    float* gram   = W + 64;       // 4096
    float* sstat  = W + 4160;     // 48
    float* ostat  = W + 4208;     // 512  (zero region ends 4720)
    float* weffT  = W + 4720;     // 16384 ([c][o])
    float* beff   = W + 21104;    // 256
    float* scoef  = W + 21360;    // 24
    float* ocoef  = W + 21384;    // 512
    int*   flag   = (int*)(W + 21896);    // 1 (+3 pad)
    u16*   qe     = (u16*)(W + 21900);    // 8*2304 u16
    u16*   keT    = (u16*)(W + 31116);    // 8*2304 u16
    u16*   ve     = (u16*)(W + 40332);    // 16*2304 u16; ends at 58764
    // region1 (14155776 f): x2 f32 [b][h][c] (7077888 f) then clobbered by pre2
    float* x2     = W + 58764;
    u16*   pre2   = (u16*)(W + 58764);
    u16*   qkv    = (u16*)(W + 58764 + 14155776);   // 28311552 u16

    k_detect<<<1, 256, 0, stream>>>((const u16*)X, flag);
    k_zero<<<8, 256, 0, stream>>>(W);
    k_emb<<<9, 256, 0, stream>>>(rel, fidx, flag, qe, keT, ve);
    k_gram<<<576, 256, 0, stream>>>(X, flag, musum, gram, x2);
    k_fold<<<1, 256, 0, stream>>>(Wkv, Wq, gkv, bkv, gq, bq, flag, musum, gram, weffT, beff);
    k_stage1<<<2304, 256, 0, stream>>>(x2, weffT, beff, qe, keT, fqrp, fkrp, flag, sstat, qkv);
    k_simcoef<<<1, 32, 0, stream>>>(sstat, gsim, flag, scoef);
    k_attn2<<<dim3(2304, 8), 256, 0, stream>>>(qkv, qe, keT, ve, scoef,
                                               fqrp, fkrp, fsvp, fsvep, flag, ostat, pre2);
    k_outcoef<<<1, 256, 0, stream>>>(ostat, gout, bout, flag, ocoef);
    k_final<<<dim3(128, 48), 256, 0, stream>>>(pre2, ocoef, flag, d_out);
}